// Round 6
// baseline (281.418 us; speedup 1.0000x reference)
//
#include <hip/hip_runtime.h>
#include <hip/hip_bf16.h>

// Round 6: R5 with the qkv V-transpose store fixed (was writing only half of
// each V^T row, leaving poisoned data -> absmax 0.53).
//   k1 qkv: m=64/block, grid 512. A staged once; B reg-prefetch; V^T via full
//           LDS-transpose bounce (4 int4/thread).
//   k2 attn: 32x32x16 MFMA, q=32/wave, 128q/block, 8 waves (4 qw x 2 kv-halves),
//           BN=32, double-buffered global_load_lds (128KB), LDS merge.
//   k3 proj: unchanged.
// ws (ushort): Q/ctx[0], K[NE], Vt[2NE], NE=16*2048*256.

typedef short bf16x8 __attribute__((ext_vector_type(8)));
typedef float f32x4 __attribute__((ext_vector_type(4)));
typedef float f32x16 __attribute__((ext_vector_type(16)));

#define MFMA16(a, b, c) __builtin_amdgcn_mfma_f32_16x16x32_bf16((a), (b), (c), 0, 0, 0)
#define MFMA32(a, b, c) __builtin_amdgcn_mfma_f32_32x32x16_bf16((a), (b), (c), 0, 0, 0)

__device__ __forceinline__ unsigned short f2bf(float f) {
  unsigned int x;
  __builtin_memcpy(&x, &f, 4);
  x = x + 0x7fffu + ((x >> 16) & 1u);
  return (unsigned short)(x >> 16);
}
__device__ __forceinline__ unsigned int pack2(float a, float b) {
  float2 t;
  t.x = a;
  t.y = b;
  __hip_bfloat162 h = __float22bfloat162_rn(t);
  unsigned int u;
  __builtin_memcpy(&u, &h, 4);
  return u;
}

typedef __attribute__((address_space(3))) void as3_void;
typedef __attribute__((address_space(1))) const void as1_void;
__device__ __forceinline__ void gl_lds16(const void* g, void* l) {
  __builtin_amdgcn_global_load_lds((as1_void*)(unsigned long long)g,
                                   (as3_void*)(unsigned int)(unsigned long long)l,
                                   16, 0, 0);
}

// ---------------- QKV GEMM ----------------
// grid(512), block 256 (4 waves), 2 blocks/CU. Block: 64 m-rows, full n=768 in
// 6 n-tiles x 4 kb-stages. A LDS once; B reg-prefetch -> 16KB LDS buffer.
__global__ __launch_bounds__(256, 2) void qkv_kernel(
    const float* __restrict__ X, const float* __restrict__ W,
    unsigned short* __restrict__ Q, unsigned short* __restrict__ Kp,
    unsigned short* __restrict__ Vt) {
  __shared__ unsigned short Al[64 * 256];  // 32KB, chunk swz j'=(j&24)|((j^(m&7))&7)
  __shared__ unsigned short Bl[128 * 64];  // 16KB, chunk swz j'=j^(n&7)
  __shared__ unsigned short Vl[128 * 72];  // 18KB transpose bounce (pad 72)
  const int m0 = blockIdx.x * 64;
  const int t = threadIdx.x;
  const int w = t >> 6, lane = t & 63, lo = lane & 15, quad = lane >> 4;
  const int aw = (w >> 1) * 32, bw = (w & 1) * 64;
  const int bb = m0 >> 11, s0 = m0 & 2047;

  // stage A once (fp32 -> bf16)
#pragma unroll
  for (int i = 0; i < 8; ++i) {
    int ci = i * 256 + t;
    int m = ci >> 5, j = ci & 31;
    int jd = (j & 24) | ((j ^ (m & 7)) & 7);
    const float* xp = X + (size_t)(m0 + m) * 256 + j * 8;
    float4 a0 = *(const float4*)xp, a1 = *(const float4*)(xp + 4);
    uint4 ua;
    ua.x = pack2(a0.x, a0.y);
    ua.y = pack2(a0.z, a0.w);
    ua.z = pack2(a1.x, a1.y);
    ua.w = pack2(a1.z, a1.w);
    *(uint4*)(&Al[m * 256 + jd * 8]) = ua;
  }

  // prefetch B stage 0 into regs
  float4 pf[8];
  const int cn = (t >> 3), cj = t & 7;  // 4 B-chunk rows: cn+32i, k-chunk cj
#pragma unroll
  for (int i = 0; i < 4; ++i) {
    const float* wp = W + (size_t)(cn + 32 * i) * 256 + cj * 8;  // stage0
    pf[2 * i] = *(const float4*)wp;
    pf[2 * i + 1] = *(const float4*)(wp + 4);
  }

  f32x4 zero4 = {0.f, 0.f, 0.f, 0.f};
  f32x4 acc[2][4];
#pragma unroll
  for (int i = 0; i < 2; i++)
#pragma unroll
    for (int j = 0; j < 4; j++) acc[i][j] = zero4;

  __syncthreads();  // A ready

  for (int s = 0; s < 24; ++s) {
    // write prefetched B (stage s) to LDS
#pragma unroll
    for (int i = 0; i < 4; ++i) {
      int n = cn + 32 * i;
      int jd = cj ^ (n & 7);
      uint4 ub;
      ub.x = pack2(pf[2 * i].x, pf[2 * i].y);
      ub.y = pack2(pf[2 * i].z, pf[2 * i].w);
      ub.z = pack2(pf[2 * i + 1].x, pf[2 * i + 1].y);
      ub.w = pack2(pf[2 * i + 1].z, pf[2 * i + 1].w);
      *(uint4*)(&Bl[n * 64 + jd * 8]) = ub;
    }
    __syncthreads();
    // prefetch stage s+1
    if (s < 23) {
      int s1 = s + 1;
      int nt1 = s1 >> 2, kb1 = s1 & 3;
#pragma unroll
      for (int i = 0; i < 4; ++i) {
        const float* wp =
            W + (size_t)(nt1 * 128 + cn + 32 * i) * 256 + kb1 * 64 + cj * 8;
        pf[2 * i] = *(const float4*)(wp);
        pf[2 * i + 1] = *(const float4*)(wp + 4);
      }
    }
    const int kb = s & 3;
#pragma unroll
    for (int kst = 0; kst < 2; ++kst) {
      int c = kb * 8 + kst * 4 + quad;
      int jjA = (c & 24) | ((c ^ (lo & 7)) & 7);
      bf16x8 af[2], bfr[4];
#pragma unroll
      for (int mt = 0; mt < 2; ++mt)
        af[mt] = *(const bf16x8*)(&Al[(aw + mt * 16 + lo) * 256 + jjA * 8]);
#pragma unroll
      for (int nt = 0; nt < 4; ++nt) {
        int nrow = bw + nt * 16 + lo;
        int jjB = (kst * 4 + quad) ^ (nrow & 7);
        bfr[nt] = *(const bf16x8*)(&Bl[nrow * 64 + jjB * 8]);
      }
#pragma unroll
      for (int mt = 0; mt < 2; ++mt)
#pragma unroll
        for (int nt = 0; nt < 4; ++nt)
          acc[mt][nt] = MFMA16(af[mt], bfr[nt], acc[mt][nt]);
    }

    if (kb == 3) {  // n-tile complete: epilogue
      const int n_t = s >> 2;
      if (n_t < 4) {  // Q (0,1) or K (2,3)
        unsigned short* base = (n_t < 2) ? Q : Kp;
        int noff = (n_t < 2) ? n_t * 128 : (n_t - 2) * 128;
#pragma unroll
        for (int mt = 0; mt < 2; ++mt)
#pragma unroll
          for (int nt = 0; nt < 4; ++nt) {
            int m = m0 + aw + mt * 16 + quad * 4;
            int n = noff + bw + nt * 16 + lo;
            unsigned short* p = base + (size_t)m * 256 + n;
            p[0] = f2bf(acc[mt][nt][0]);
            p[256] = f2bf(acc[mt][nt][1]);
            p[512] = f2bf(acc[mt][nt][2]);
            p[768] = f2bf(acc[mt][nt][3]);
            acc[mt][nt] = zero4;
          }
      } else {  // V: transpose via LDS bounce, coalesced row stores
        const int dbase = (n_t - 4) * 128;
#pragma unroll
        for (int mt = 0; mt < 2; ++mt)
#pragma unroll
          for (int nt = 0; nt < 4; ++nt) {
            int sl = aw + mt * 16 + quad * 4;
            int dl = bw + nt * 16 + lo;
            uint2 v;
            v.x = pack2(acc[mt][nt][0], acc[mt][nt][1]);
            v.y = pack2(acc[mt][nt][2], acc[mt][nt][3]);
            *(uint2*)(&Vl[dl * 72 + sl]) = v;
            acc[mt][nt] = zero4;
          }
        __syncthreads();
        {
          // FIX (R5 bug): full row coverage — 2 threads/row x 32 ushorts each
          int dl = t >> 1, part = t & 1;
          int off = dl * 72 + part * 32;
          int4 v0 = *(const int4*)(&Vl[off]);
          int4 v1 = *(const int4*)(&Vl[off + 8]);
          int4 v2 = *(const int4*)(&Vl[off + 16]);
          int4 v3 = *(const int4*)(&Vl[off + 24]);
          unsigned short* gp =
              Vt + ((size_t)(bb * 256 + dbase + dl)) * 2048 + s0 + part * 32;
          *(int4*)gp = v0;
          *(int4*)(gp + 8) = v1;
          *(int4*)(gp + 16) = v2;
          *(int4*)(gp + 24) = v3;
        }
      }
    }
    __syncthreads();
  }
}

// ---------------- Flash attention: 32x32 MFMA, split-KV, async dbuf ----------------
// grid(256): id = qt*16 + b  (all 16 q-tiles of a batch -> same XCD, KV L2-resident).
// block 512 = 8 waves: qw = w&3 (32 q-rows), h = w>>2 (kv half, 32 iters BN=32).
// LDS buffer (64KB x2): K [h][sk 32][256] chunk-XOR-src-swizzled; V [h][j 0..3][d 256].
__global__ __launch_bounds__(512, 2) void attn_kernel(
    const unsigned short* __restrict__ Q, const unsigned short* __restrict__ K,
    const unsigned short* __restrict__ Vt, unsigned short* __restrict__ C) {
  __shared__ __attribute__((aligned(16))) unsigned short smem[65536];  // 128KB
  const int id = blockIdx.x;
  const int qt = id >> 4, b = id & 15;
  const int t = threadIdx.x;
  const int w = t >> 6, lane = t & 63;
  const int l31 = lane & 31, hi = lane >> 5;
  const int h = w >> 2, qw = w & 3;
  constexpr float SCALE_LOG2E = 0.0625f * 1.4426950408889634f;

  const unsigned short* Kb = K + (size_t)b * 2048 * 256;
  const unsigned short* Vb = Vt + (size_t)b * 256 * 2048;

  unsigned int koff[4], voff[4];
  int ldsK[4], ldsV[4];
#pragma unroll
  for (int r = 0; r < 4; ++r) {
    int cl = r * 512 + t;
    int hc = cl >> 10, rem = cl & 1023;
    int sk = rem >> 5, j = rem & 31;
    int jj = (j & 16) | ((j ^ (sk & 15)) & 15);
    koff[r] = (unsigned int)(((hc * 1024 + sk) * 256 + jj * 8) * 2);  // bytes
    ldsK[r] = cl * 8;
    int vj = rem >> 8, vd = rem & 255;
    voff[r] = (unsigned int)((vd * 2048 + hc * 1024 + vj * 8) * 2);  // bytes
    ldsV[r] = 16384 + cl * 8;
  }

  // Q fragments (B-operand, 32x32x16): lane: q = l31, k = 16*kst + 8*hi + 0..7
  const int qrow = b * 2048 + qt * 128 + qw * 32 + l31;
  const unsigned short* qp = Q + (size_t)qrow * 256;
  bf16x8 qf[16];
#pragma unroll
  for (int kst = 0; kst < 16; ++kst)
    qf[kst] = *(const bf16x8*)(qp + kst * 16 + hi * 8);

  f32x16 oacc[8];
#pragma unroll
  for (int dg = 0; dg < 8; ++dg)
#pragma unroll
    for (int i = 0; i < 16; ++i) oacc[dg][i] = 0.f;
  float m_run = -1e30f, l_run = 0.f;

  // prologue: prefetch iter 0 into buffer 0
#pragma unroll
  for (int r = 0; r < 4; ++r) gl_lds16((const char*)Kb + koff[r], &smem[ldsK[r]]);
#pragma unroll
  for (int r = 0; r < 4; ++r) gl_lds16((const char*)Vb + voff[r], &smem[ldsV[r]]);
#pragma unroll
  for (int r = 0; r < 4; ++r) {
    koff[r] += 32 * 256 * 2;
    voff[r] += 32 * 2;
  }

  for (int it = 0; it < 32; ++it) {
    asm volatile("s_waitcnt vmcnt(0)" ::: "memory");
    __syncthreads();
    if (it < 31) {
      const int pn = ((it + 1) & 1) * 32768;
#pragma unroll
      for (int r = 0; r < 4; ++r)
        gl_lds16((const char*)Kb + koff[r], &smem[pn + ldsK[r]]);
#pragma unroll
      for (int r = 0; r < 4; ++r)
        gl_lds16((const char*)Vb + voff[r], &smem[pn + ldsV[r]]);
#pragma unroll
      for (int r = 0; r < 4; ++r) {
        koff[r] += 32 * 256 * 2;
        voff[r] += 32 * 2;
      }
    }
    const unsigned short* Kl = smem + (it & 1) * 32768 + h * 8192;
    const unsigned short* Vl = smem + (it & 1) * 32768 + 16384 + h * 8192;

    // S^T[32 sk][32 q] = K * Q^T
    f32x16 sacc;
#pragma unroll
    for (int i = 0; i < 16; ++i) sacc[i] = 0.f;
#pragma unroll
    for (int kst = 0; kst < 16; ++kst) {
      int jg = 2 * kst + hi;
      int jl = (jg & 16) | ((jg ^ (lane & 15)) & 15);
      bf16x8 kf = *(const bf16x8*)(&Kl[(l31 * 32 + jl) * 8]);
      sacc = MFMA32(kf, qf[kst], sacc);
    }

    // online softmax: lane owns q=l31, 16 sk values (partner lane^32 has rest)
    float p[16];
    float cmax = -1e30f;
#pragma unroll
    for (int i = 0; i < 16; ++i) {
      p[i] = sacc[i] * SCALE_LOG2E;
      cmax = fmaxf(cmax, p[i]);
    }
    cmax = fmaxf(cmax, __shfl_xor(cmax, 32));
    float mnew = fmaxf(m_run, cmax);
    if (__any(cmax > m_run)) {
      float alpha = exp2f(m_run - mnew);
      l_run *= alpha;
#pragma unroll
      for (int dg = 0; dg < 8; ++dg)
#pragma unroll
        for (int i = 0; i < 16; ++i) oacc[dg][i] *= alpha;
      m_run = mnew;
    }
    float rsum = 0.f;
#pragma unroll
    for (int i = 0; i < 16; ++i) {
      p[i] = exp2f(p[i] - m_run);
      rsum += p[i];
    }
    rsum += __shfl_xor(rsum, 32);
    l_run += rsum;

    // P^T B-frags: dword d of kstep ks from lane (l31 | (d>>1)<<5),
    // value pk[2ks+hi][d&1]
    unsigned int pk[4][2];
#pragma unroll
    for (int g = 0; g < 4; ++g) {
      pk[g][0] = pack2(p[4 * g], p[4 * g + 1]);
      pk[g][1] = pack2(p[4 * g + 2], p[4 * g + 3]);
    }
    bf16x8 pfr[2];
#pragma unroll
    for (int ks = 0; ks < 2; ++ks) {
      union {
        unsigned int u[4];
        bf16x8 v;
      } cvt;
#pragma unroll
      for (int d = 0; d < 4; ++d) {
        int src = l31 + ((d >> 1) << 5);
        unsigned int v0 = (unsigned int)__shfl((int)pk[2 * ks][d & 1], src);
        unsigned int v1 = (unsigned int)__shfl((int)pk[2 * ks + 1][d & 1], src);
        cvt.u[d] = hi ? v1 : v0;
      }
      pfr[ks] = cvt.v;
    }

    // O^T[256 d][32 q] += V^T * P^T
#pragma unroll
    for (int dg = 0; dg < 8; ++dg) {
#pragma unroll
      for (int ks = 0; ks < 2; ++ks) {
        bf16x8 vf =
            *(const bf16x8*)(&Vl[((2 * ks + hi) * 256 + dg * 32 + l31) * 8]);
        oacc[dg] = MFMA32(vf, pfr[ks], oacc[dg]);
      }
    }
  }

  // ---- merge kv-halves (partner wave w^4), 2 rounds of 128 d ----
  float* st = (float*)smem;  // m[8][32], l[8][32]
  if (hi == 0) {
    st[w * 32 + l31] = m_run;
    st[256 + w * 32 + l31] = l_run;
  }
  __syncthreads();
  float m_o = st[(w ^ 4) * 32 + l31];
  float l_o = st[256 + (w ^ 4) * 32 + l31];
  float m_tot = fmaxf(m_run, m_o);
  float f_self = exp2f(m_run - m_tot);
  float l_tot = l_run * f_self + l_o * exp2f(m_o - m_tot);
  float inv = 1.0f / l_tot;
  float* Of = (float*)smem + 512;  // [qw][128 d][32 q] floats
  unsigned short* cp = C + (size_t)qrow * 256;
#pragma unroll
  for (int rd = 0; rd < 2; ++rd) {
    if (h == 1) {
#pragma unroll
      for (int dgl = 0; dgl < 4; ++dgl) {
        int dg = rd * 4 + dgl;
#pragma unroll
        for (int r = 0; r < 16; ++r) {
          int dl = dgl * 32 + (r & 3) + 8 * (r >> 2) + 4 * hi;
          Of[qw * 4096 + dl * 32 + l31] = oacc[dg][r] * f_self;
        }
      }
    }
    __syncthreads();
    if (h == 0) {
#pragma unroll
      for (int dgl = 0; dgl < 4; ++dgl) {
        int dg = rd * 4 + dgl;
#pragma unroll
        for (int rq = 0; rq < 4; ++rq) {
          int dl = dgl * 32 + 8 * rq + 4 * hi;
          float o0 = oacc[dg][rq * 4 + 0] * f_self + Of[qw * 4096 + (dl + 0) * 32 + l31];
          float o1 = oacc[dg][rq * 4 + 1] * f_self + Of[qw * 4096 + (dl + 1) * 32 + l31];
          float o2 = oacc[dg][rq * 4 + 2] * f_self + Of[qw * 4096 + (dl + 2) * 32 + l31];
          float o3 = oacc[dg][rq * 4 + 3] * f_self + Of[qw * 4096 + (dl + 3) * 32 + l31];
          uint2 v;
          v.x = pack2(o0 * inv, o1 * inv);
          v.y = pack2(o2 * inv, o3 * inv);
          *(uint2*)(cp + rd * 128 + dgl * 32 + 8 * rq + 4 * hi) = v;
        }
      }
    }
    __syncthreads();
  }
}

// ---------------- Output projection ----------------
__global__ __launch_bounds__(256, 3) void proj_kernel(
    const unsigned short* __restrict__ Xc, const float* __restrict__ W,
    const float* __restrict__ bias, float* __restrict__ out) {
  __shared__ unsigned short Al[128 * 64];
  __shared__ unsigned short Bl[128 * 64];
  const int n0 = blockIdx.x * 128;
  const int m0 = blockIdx.y * 128;
  const int t = threadIdx.x;
  const int w = t >> 6, lane = t & 63, lo = lane & 15, quad = lane >> 4;
  const int aw = (w >> 1) * 64, bw = (w & 1) * 64;

  f32x4 zero4 = {0.f, 0.f, 0.f, 0.f};
  f32x4 acc[4][4];
#pragma unroll
  for (int i = 0; i < 4; i++)
#pragma unroll
    for (int j = 0; j < 4; j++) acc[i][j] = zero4;

  for (int kb = 0; kb < 4; ++kb) {
    const int k0 = kb * 64;
#pragma unroll
    for (int rr = 0; rr < 4; ++rr) {
      int ci = rr * 256 + t;
      int row = ci >> 3, c = ci & 7, cs = c ^ (row & 7);
      *(int4*)(&Al[row * 64 + cs * 8]) =
          *(const int4*)(Xc + (size_t)(m0 + row) * 256 + k0 + c * 8);
      const float* wp = W + (size_t)(n0 + row) * 256 + k0 + c * 8;
      float4 b0 = *(const float4*)wp, b1 = *(const float4*)(wp + 4);
      uint4 ub;
      ub.x = pack2(b0.x, b0.y);
      ub.y = pack2(b0.z, b0.w);
      ub.z = pack2(b1.x, b1.y);
      ub.w = pack2(b1.z, b1.w);
      *(uint4*)(&Bl[row * 64 + cs * 8]) = ub;
    }
    __syncthreads();
#pragma unroll
    for (int ks = 0; ks < 2; ++ks) {
      const int c = ks * 4 + quad, cs = c ^ (lo & 7);
      bf16x8 af[4], bfr[4];
#pragma unroll
      for (int mt = 0; mt < 4; ++mt)
        af[mt] = *(const bf16x8*)(&Al[(aw + mt * 16 + lo) * 64 + cs * 8]);
#pragma unroll
      for (int nt = 0; nt < 4; ++nt)
        bfr[nt] = *(const bf16x8*)(&Bl[(bw + nt * 16 + lo) * 64 + cs * 8]);
#pragma unroll
      for (int mt = 0; mt < 4; ++mt)
#pragma unroll
        for (int nt = 0; nt < 4; ++nt)
          acc[mt][nt] = MFMA16(af[mt], bfr[nt], acc[mt][nt]);
    }
    __syncthreads();
  }

  const int mb = m0 + aw, nb = n0 + bw;
#pragma unroll
  for (int mt = 0; mt < 4; ++mt)
#pragma unroll
    for (int nt = 0; nt < 4; ++nt) {
      int m = mb + mt * 16 + quad * 4;
      int n = nb + nt * 16 + lo;
      float bv = bias[n];
      float* p = out + (size_t)m * 256 + n;
      p[0] = acc[mt][nt][0] + bv;
      p[256] = acc[mt][nt][1] + bv;
      p[512] = acc[mt][nt][2] + bv;
      p[768] = acc[mt][nt][3] + bv;
    }
}

extern "C" void kernel_launch(void* const* d_in, const int* in_sizes, int n_in,
                              void* d_out, int out_size, void* d_ws, size_t ws_size,
                              hipStream_t stream) {
  const float* X = (const float*)d_in[0];
  const float* Wq = (const float*)d_in[1];
  const float* Wo = (const float*)d_in[2];
  const float* Bo = (const float*)d_in[3];
  float* out = (float*)d_out;
  unsigned short* ws = (unsigned short*)d_ws;

  const size_t NE = (size_t)16 * 2048 * 256;
  unsigned short* Qb = ws;
  unsigned short* Kb = ws + NE;
  unsigned short* Vt = ws + 2 * NE;
  unsigned short* Cx = ws;  // ctx aliases Q (per-block private rows)

  qkv_kernel<<<dim3(512), 256, 0, stream>>>(X, Wq, Qb, Kb, Vt);
  attn_kernel<<<dim3(256), 512, 0, stream>>>(Qb, Kb, Vt, Cx);
  proj_kernel<<<dim3(2, 256), 256, 0, stream>>>(Cx, Wo, Bo, out);
}